// Round 1
// 305.667 us; speedup vs baseline: 1.0091x; 1.0091x over previous
//
#include <hip/hip_runtime.h>
#include <math.h>

#define R_ 4
#define B_ 16
#define HQ_ 32
#define HKV_ 2
#define G_ 16
#define D_ 128
#define S_ 32
#define L_ 2048
#define P_ 32768
#define TS_ 64
#define KSTR 136   // halves per k_s/q_s row: 272B, 16B-aligned rows
#define PSTR 18    // floats per p_s row: even stride for 8B-aligned float2 reads
#define NEGINF (-INFINITY)

typedef _Float16 h4 __attribute__((ext_vector_type(4)));
typedef _Float16 h8 __attribute__((ext_vector_type(8)));
typedef float    fx4 __attribute__((ext_vector_type(4)));

// ws layout:
//   lse_split [R][B][HKV][S][G]  float   = 65536 f
//   chunk_m   [R][B][HKV][S][G]  float   = 65536 f
//   chunk_acc [R][B][HKV][S][G][D] half  = 8388608 h (16.8 MB)

__global__ __launch_bounds__(256, 6) void fd_stage1(
    const float* __restrict__ q, const float* __restrict__ kc,
    const float* __restrict__ vc, const int* __restrict__ bt,
    const int* __restrict__ lens,
    float* __restrict__ lse_split, float* __restrict__ chunk_m,
    _Float16* __restrict__ chunk_acc)
{
  const int t   = threadIdx.x;
  const int blk = blockIdx.x;
  const int s   = blk & 31;
  const int hkv = (blk >> 5) & 1;
  const int b   = (blk >> 6) & 15;
  const int r   = blk >> 10;

  const int len = lens[r*B_ + b];
  const int per = (len + 31) >> 5;        // ceil(len/32), 2..64
  const int n0  = s*per;
  const int tn  = min(per, len - n0);     // block-uniform

  float* lse_out = lse_split + ((r*B_ + b)*HKV_ + hkv)*(S_*G_);
  const int cmbase = (((r*B_ + b)*HKV_ + hkv)*S_ + s)*G_;
  _Float16* ca = chunk_acc + (size_t)(((r*B_ + b)*HKV_ + hkv)*S_ + s)*(G_*D_);

  if (tn <= 0) {                          // empty split: -inf lse/m, zero acc
    if (t < G_) { lse_out[s*G_ + t] = NEGINF; chunk_m[cmbase + t] = NEGINF; }
    h8 z = {};
    *(h8*)&ca[t*8] = z;                   // 256 thr x 8 halves = G_*D_
    return;
  }

  __shared__ _Float16 q_s[G_][KSTR];                  // 4352 B
  __shared__ _Float16 k_s[TS_][KSTR];                 // 17408 B
  __shared__ __align__(16) float p_s[TS_][PSTR];      // 4608 B
  __shared__ int pg_s[TS_];                           // 256 B  (total 26624 B -> 6 blk/CU)
  // cross-wave softmax exchange buffer overlaid on p_s (p_s dead until after it)
  float2* red = (float2*)&p_s[0][0];                  // [4 waves][16 heads]

  const int* btb   = bt + (r*B_ + b)*L_;
  const int kvbase = r*(P_*HKV_*D_) + hkv*D_;

  // prefetch page table slice (n0+63 <= 2047, always in-bounds; tails unused)
  if (t < TS_) pg_s[t] = btb[n0 + t];

  // stage Q (fp32 -> fp16): 16 heads x 128, coalesced
  {
    const float* qb = q + (b*HQ_ + hkv*G_)*D_;
    int fi = t;
    #pragma unroll
    for (int i = 0; i < 2; ++i, fi += 256) {
      const int g = fi >> 5, dd = (fi & 31)*4;
      const float4 v = *(const float4*)&qb[g*D_ + dd];
      h4 hv; hv.x=(_Float16)v.x; hv.y=(_Float16)v.y; hv.z=(_Float16)v.z; hv.w=(_Float16)v.w;
      *(h4*)&q_s[g][dd] = hv;
    }
  }

  // stage K rows (fp32 -> fp16): 8 rows in parallel, 32 lanes x 4 elems
  {
    const int lane = t & 31, rw = t >> 5;
    for (int row = rw; row < tn; row += 8) {
      const int pg = btb[n0 + row];       // 32-lane broadcast, L1/L2
      const float4 v = *(const float4*)&kc[kvbase + pg*(HKV_*D_) + lane*4];
      h4 hv; hv.x=(_Float16)v.x; hv.y=(_Float16)v.y; hv.z=(_Float16)v.z; hv.w=(_Float16)v.w;
      *(h4*)&k_s[row][lane*4] = hv;
    }
  }
  __syncthreads();

  // ---- scores via MFMA: wave w computes D[token 16w..16w+15][head 0..15].
  // A[token][k] = k_s row (lane&15 -> token, 8*(lane>>4)+j -> k), contiguous h8.
  // B[k][head]  = Q[head][k] = q_s row, same contiguous addressing.
  // C/D: col(head)=lane&15, row(token_local)=4*(lane>>4)+reg  [m89 mapping].
  const int w  = t >> 6;                  // wave 0..3
  const int l  = t & 63;
  const int hh = l & 15;                  // head
  const int tq = l >> 4;                  // token quad / k-group
  const bool active = (16*w) < tn;        // wave-uniform

  fx4 dacc = {0.f, 0.f, 0.f, 0.f};
  if (active) {
    #pragma unroll
    for (int c = 0; c < 4; ++c) {         // K = 4 x 32 = 128
      const h8 af = *(const h8*)&k_s[16*w + hh][c*32 + 8*tq];
      const h8 bf = *(const h8*)&q_s[hh][c*32 + 8*tq];
      dacc = __builtin_amdgcn_mfma_f32_16x16x32_f16(af, bf, dacc, 0, 0, 0);
    }
  }

  const float sc = 0.08838834764831845f;  // 128^-0.5
  const int nb = 16*w + 4*tq;             // this lane's token row base
  const float sv0 = (nb + 0 < tn) ? dacc[0]*sc : NEGINF;
  const float sv1 = (nb + 1 < tn) ? dacc[1]*sc : NEGINF;
  const float sv2 = (nb + 2 < tn) ? dacc[2]*sc : NEGINF;
  const float sv3 = (nb + 3 < tn) ? dacc[3]*sc : NEGINF;

  // wave-local per-head max over this wave's 16 tokens (lanes h, h+16, h+32, h+48)
  float pmw = fmaxf(fmaxf(sv0, sv1), fmaxf(sv2, sv3));
  pmw = fmaxf(pmw, __shfl_xor(pmw, 16));
  pmw = fmaxf(pmw, __shfl_xor(pmw, 32));
  const float pms = (pmw == NEGINF) ? 0.f : pmw;  // avoid (-inf)-(-inf)=NaN
  const float e0 = __expf(sv0 - pms);
  const float e1 = __expf(sv1 - pms);
  const float e2 = __expf(sv2 - pms);
  const float e3 = __expf(sv3 - pms);
  float psw = e0 + e1 + e2 + e3;
  psw += __shfl_xor(psw, 16);
  psw += __shfl_xor(psw, 32);

  if (l < 16) red[w*16 + l] = make_float2(pmw, psw);
  __syncthreads();

  // cross-wave combine: pm = split max, ps = sum exp(s - pm) over all 64 tokens
  const float2 rr0 = red[hh], rr1 = red[16 + hh], rr2 = red[32 + hh], rr3 = red[48 + hh];
  const float pm = fmaxf(fmaxf(rr0.x, rr1.x), fmaxf(rr2.x, rr3.x));
  const float ps = rr0.y*__expf(rr0.x - pm) + rr1.y*__expf(rr1.x - pm)
                 + rr2.y*__expf(rr2.x - pm) + rr3.y*__expf(rr3.x - pm);

  if (w == 0 && l < 16) {
    lse_out[s*G_ + l]   = pm + __logf(ps);  // exact per-split lse
    chunk_m[cmbase + l] = pm;               // split max
  }
  __syncthreads();                          // red reads done before p_s overwrite

  // p transposed: p_s[n][h] = exp(s - pm); invalid rows -> 0
  if (active) {
    const float cw = __expf(pmw - pm);      // pmw=-inf -> 0
    p_s[nb + 0][hh] = e0*cw;
    p_s[nb + 1][hh] = e1*cw;
    p_s[nb + 2][hh] = e2*cw;
    p_s[nb + 3][hh] = e3*cw;
  }
  __syncthreads();

  // PV: thread owns head pair (g2, g2+1) x dims d4..d4+3; V straight from global,
  // page index from LDS (no dependent btb->V global chain)
  const int d4 = (t & 31)*4;
  const int g2 = (t >> 5)*2;
  float4 a0 = make_float4(0.f,0.f,0.f,0.f);
  float4 a1 = make_float4(0.f,0.f,0.f,0.f);
  #pragma unroll 4
  for (int n = 0; n < tn; ++n) {
    const int pg = pg_s[n];                 // LDS broadcast
    const float4 v4 = *(const float4*)&vc[kvbase + pg*(HKV_*D_) + d4];
    const float2 pp = *(const float2*)&p_s[n][g2];
    a0.x += pp.x*v4.x; a0.y += pp.x*v4.y; a0.z += pp.x*v4.z; a0.w += pp.x*v4.w;
    a1.x += pp.y*v4.x; a1.y += pp.y*v4.y; a1.z += pp.y*v4.z; a1.w += pp.y*v4.w;
  }

  h4 o0; o0.x=(_Float16)a0.x; o0.y=(_Float16)a0.y; o0.z=(_Float16)a0.z; o0.w=(_Float16)a0.w;
  h4 o1; o1.x=(_Float16)a1.x; o1.y=(_Float16)a1.y; o1.z=(_Float16)a1.z; o1.w=(_Float16)a1.w;
  *(h4*)&ca[g2*D_ + d4]       = o0;
  *(h4*)&ca[(g2 + 1)*D_ + d4] = o1;
}

__global__ __launch_bounds__(128) void fd_stage2(
    const float* __restrict__ lse_split, const float* __restrict__ chunk_m,
    const _Float16* __restrict__ chunk_acc, float* __restrict__ out)
{
  const int bh  = blockIdx.x;          // b*32 + h
  const int b   = bh >> 5, h = bh & 31;
  const int hkv = h >> 4, g = h & 15;
  const int d   = threadIdx.x;

  float m_r[R_], lse_r[R_];
  #pragma unroll
  for (int r = 0; r < R_; ++r) {
    const float* ls = lse_split + ((r*B_ + b)*HKV_ + hkv)*(S_*G_) + g;
    float m = NEGINF;
    #pragma unroll 8
    for (int s2 = 0; s2 < S_; ++s2) m = fmaxf(m, ls[s2*G_]);
    float sum = 0.f;
    #pragma unroll 8
    for (int s2 = 0; s2 < S_; ++s2) sum += __expf(ls[s2*G_] - m);
    m_r[r]   = m;
    lse_r[r] = m + __logf(sum);
  }
  const float M = fmaxf(fmaxf(lse_r[0], lse_r[1]), fmaxf(lse_r[2], lse_r[3]));
  float denom = 0.f, o = 0.f;
  #pragma unroll
  for (int r = 0; r < R_; ++r) {
    const float w = __expf(lse_r[r] - M);
    denom += w;
    const float* cm = chunk_m + (((r*B_ + b)*HKV_ + hkv)*S_)*G_ + g;
    const _Float16* ca = chunk_acc
        + (size_t)(((r*B_ + b)*HKV_ + hkv)*S_)*(G_*D_) + g*D_ + d;
    float a = 0.f;
    #pragma unroll 8
    for (int c = 0; c < S_; ++c)
      a += __expf(cm[c*G_] - m_r[r]) * (float)ca[(size_t)c*(G_*D_)];
    o += w * a;   // faithful: acc_r UNNORMALIZED, weighted by exp(lse_r - M)
  }
  out[(size_t)bh*D_ + d] = o / denom;
}

extern "C" void kernel_launch(void* const* d_in, const int* in_sizes, int n_in,
                              void* d_out, int out_size, void* d_ws, size_t ws_size,
                              hipStream_t stream) {
  const float* q   = (const float*)d_in[0];
  const float* kc  = (const float*)d_in[1];
  const float* vc  = (const float*)d_in[2];
  const int*   bt  = (const int*)d_in[3];
  const int*   len = (const int*)d_in[4];
  float* out = (float*)d_out;
  float* ws  = (float*)d_ws;

  const size_t lse_f = (size_t)R_*B_*HKV_*S_*G_;   // 65536
  float*    lse_split = ws;
  float*    chunk_m   = ws + lse_f;
  _Float16* chunk_acc = (_Float16*)(ws + 2*lse_f);

  fd_stage1<<<dim3(R_*B_*HKV_*S_), dim3(256), 0, stream>>>(
      q, kc, vc, bt, len, lse_split, chunk_m, chunk_acc);
  fd_stage2<<<dim3(B_*HQ_), dim3(128), 0, stream>>>(
      lse_split, chunk_m, chunk_acc, out);
}

// Round 2
// 300.528 us; speedup vs baseline: 1.0263x; 1.0171x over previous
//
#include <hip/hip_runtime.h>
#include <math.h>

#define R_ 4
#define B_ 16
#define HQ_ 32
#define HKV_ 2
#define G_ 16
#define D_ 128
#define S_ 32
#define L_ 2048
#define P_ 32768
#define TS_ 64
#define KSTR 136   // halves per q_s row: 272B, 16B-aligned rows
#define PSTR 18    // floats per p_s row: even stride for 8B-aligned float2 reads
#define NEGINF (-INFINITY)

typedef _Float16 h4 __attribute__((ext_vector_type(4)));
typedef _Float16 h8 __attribute__((ext_vector_type(8)));
typedef float    fx4 __attribute__((ext_vector_type(4)));

// ws layout:
//   lse_split [R][B][HKV][S][G]  float   = 65536 f
//   chunk_m   [R][B][HKV][S][G]  float   = 65536 f
//   chunk_acc [R][B][HKV][S][G][D] half  = 8388608 h (16.8 MB)

__global__ __launch_bounds__(256, 8) void fd_stage1(
    const float* __restrict__ q, const float* __restrict__ kc,
    const float* __restrict__ vc, const int* __restrict__ bt,
    const int* __restrict__ lens,
    float* __restrict__ lse_split, float* __restrict__ chunk_m,
    _Float16* __restrict__ chunk_acc)
{
  const int t   = threadIdx.x;
  const int blk = blockIdx.x;
  const int s   = blk & 31;
  const int hkv = (blk >> 5) & 1;
  const int b   = (blk >> 6) & 15;
  const int r   = blk >> 10;

  const int len = lens[r*B_ + b];
  const int per = (len + 31) >> 5;        // ceil(len/32), 2..64
  const int n0  = s*per;
  const int tn  = min(per, len - n0);     // block-uniform

  float* lse_out = lse_split + ((r*B_ + b)*HKV_ + hkv)*(S_*G_);
  const int cmbase = (((r*B_ + b)*HKV_ + hkv)*S_ + s)*G_;
  _Float16* ca = chunk_acc + (size_t)(((r*B_ + b)*HKV_ + hkv)*S_ + s)*(G_*D_);

  if (tn <= 0) {                          // empty split: -inf lse/m, zero acc
    if (t < G_) { lse_out[s*G_ + t] = NEGINF; chunk_m[cmbase + t] = NEGINF; }
    h8 z = {};
    *(h8*)&ca[t*8] = z;                   // 256 thr x 8 halves = G_*D_
    return;
  }

  __shared__ _Float16 q_s[G_][KSTR];                  // 4352 B
  __shared__ __align__(16) float p_s[TS_][PSTR];      // 4608 B
  __shared__ int pg_s[TS_];                           // 256 B
  __shared__ float2 red_s[64];                        // 512 B  (total ~9.7 KB)

  const int* btb   = bt + (r*B_ + b)*L_;
  const int kvbase = r*(P_*HKV_*D_) + hkv*D_;

  // prefetch page table slice (n0+63 <= 2047, always in-bounds; tails unused)
  if (t < TS_) pg_s[t] = btb[n0 + t];

  // stage Q (fp32 -> fp16): 16 heads x 128, coalesced
  {
    const float* qb = q + (b*HQ_ + hkv*G_)*D_;
    int fi = t;
    #pragma unroll
    for (int i = 0; i < 2; ++i, fi += 256) {
      const int g = fi >> 5, dd = (fi & 31)*4;
      const float4 v = *(const float4*)&qb[g*D_ + dd];
      h4 hv; hv.x=(_Float16)v.x; hv.y=(_Float16)v.y; hv.z=(_Float16)v.z; hv.w=(_Float16)v.w;
      *(h4*)&q_s[g][dd] = hv;
    }
  }
  __syncthreads();

  // ---- scores via MFMA, K A-fragments straight from global (no K LDS stage).
  // Wave w computes D[token 16w..16w+15][head 0..15].
  // A[token][k]: lane l supplies row (l&15), k = 32c + 8*(l>>4) + j  -> two
  //   float4 loads from the row's page (line-aligned 512B rows, scattered pages).
  // B[k][head] = Q[head][k] from q_s, contiguous h8.
  // C/D: col(head)=lane&15, row(token_local)=4*(lane>>4)+reg  [m89 mapping].
  const int w  = t >> 6;                  // wave 0..3
  const int l  = t & 63;
  const int hh = l & 15;                  // head / A-row
  const int tq = l >> 4;                  // k-chunk selector
  const bool active = (16*w) < tn;        // wave-uniform

  fx4 dacc = {0.f, 0.f, 0.f, 0.f};
  if (active) {
    const int row = 16*w + hh;            // may be >= tn: real (random-page) data,
    const int pg  = pg_s[row];            // finite, masked out below
    const float* kr = kc + kvbase + pg*(HKV_*D_) + 8*tq;
    #pragma unroll
    for (int c = 0; c < 4; ++c) {         // K = 4 x 32 = 128
      const float4 f0 = *(const float4*)&kr[c*32];
      const float4 f1 = *(const float4*)&kr[c*32 + 4];
      h8 af;
      af[0]=(_Float16)f0.x; af[1]=(_Float16)f0.y; af[2]=(_Float16)f0.z; af[3]=(_Float16)f0.w;
      af[4]=(_Float16)f1.x; af[5]=(_Float16)f1.y; af[6]=(_Float16)f1.z; af[7]=(_Float16)f1.w;
      const h8 bf = *(const h8*)&q_s[hh][c*32 + 8*tq];
      dacc = __builtin_amdgcn_mfma_f32_16x16x32_f16(af, bf, dacc, 0, 0, 0);
    }
  }

  const float sc = 0.08838834764831845f;  // 128^-0.5
  const int nb = 16*w + 4*tq;             // this lane's token row base
  const float sv0 = (nb + 0 < tn) ? dacc[0]*sc : NEGINF;
  const float sv1 = (nb + 1 < tn) ? dacc[1]*sc : NEGINF;
  const float sv2 = (nb + 2 < tn) ? dacc[2]*sc : NEGINF;
  const float sv3 = (nb + 3 < tn) ? dacc[3]*sc : NEGINF;

  // wave-local per-head max over this wave's 16 tokens (lanes h, h+16, h+32, h+48)
  float pmw = fmaxf(fmaxf(sv0, sv1), fmaxf(sv2, sv3));
  pmw = fmaxf(pmw, __shfl_xor(pmw, 16));
  pmw = fmaxf(pmw, __shfl_xor(pmw, 32));
  const float pms = (pmw == NEGINF) ? 0.f : pmw;  // avoid (-inf)-(-inf)=NaN
  const float e0 = __expf(sv0 - pms);
  const float e1 = __expf(sv1 - pms);
  const float e2 = __expf(sv2 - pms);
  const float e3 = __expf(sv3 - pms);
  float psw = e0 + e1 + e2 + e3;
  psw += __shfl_xor(psw, 16);
  psw += __shfl_xor(psw, 32);

  if (l < 16) red_s[w*16 + l] = make_float2(pmw, psw);
  __syncthreads();

  // cross-wave combine: pm = split max, ps = sum exp(s - pm) over all 64 tokens
  const float2 rr0 = red_s[hh], rr1 = red_s[16 + hh];
  const float2 rr2 = red_s[32 + hh], rr3 = red_s[48 + hh];
  const float pm = fmaxf(fmaxf(rr0.x, rr1.x), fmaxf(rr2.x, rr3.x));
  const float ps = rr0.y*__expf(rr0.x - pm) + rr1.y*__expf(rr1.x - pm)
                 + rr2.y*__expf(rr2.x - pm) + rr3.y*__expf(rr3.x - pm);

  if (w == 0 && l < 16) {
    lse_out[s*G_ + l]   = pm + __logf(ps);  // exact per-split lse
    chunk_m[cmbase + l] = pm;               // split max
  }

  // p transposed: p_s[n][h] = exp(s - pm); invalid rows -> 0
  if (active) {
    const float cw = __expf(pmw - pm);      // pmw=-inf -> 0
    p_s[nb + 0][hh] = e0*cw;
    p_s[nb + 1][hh] = e1*cw;
    p_s[nb + 2][hh] = e2*cw;
    p_s[nb + 3][hh] = e3*cw;
  }
  __syncthreads();

  // PV: thread owns head pair (g2, g2+1) x dims d4..d4+3; V straight from global,
  // page index from LDS (no dependent btb->V global chain)
  const int d4 = (t & 31)*4;
  const int g2 = (t >> 5)*2;
  float4 a0 = make_float4(0.f,0.f,0.f,0.f);
  float4 a1 = make_float4(0.f,0.f,0.f,0.f);
  #pragma unroll 4
  for (int n = 0; n < tn; ++n) {
    const int pg = pg_s[n];                 // LDS broadcast
    const float4 v4 = *(const float4*)&vc[kvbase + pg*(HKV_*D_) + d4];
    const float2 pp = *(const float2*)&p_s[n][g2];
    a0.x += pp.x*v4.x; a0.y += pp.x*v4.y; a0.z += pp.x*v4.z; a0.w += pp.x*v4.w;
    a1.x += pp.y*v4.x; a1.y += pp.y*v4.y; a1.z += pp.y*v4.z; a1.w += pp.y*v4.w;
  }

  h4 o0; o0.x=(_Float16)a0.x; o0.y=(_Float16)a0.y; o0.z=(_Float16)a0.z; o0.w=(_Float16)a0.w;
  h4 o1; o1.x=(_Float16)a1.x; o1.y=(_Float16)a1.y; o1.z=(_Float16)a1.z; o1.w=(_Float16)a1.w;
  *(h4*)&ca[g2*D_ + d4]       = o0;
  *(h4*)&ca[(g2 + 1)*D_ + d4] = o1;
}

__global__ __launch_bounds__(128) void fd_stage2(
    const float* __restrict__ lse_split, const float* __restrict__ chunk_m,
    const _Float16* __restrict__ chunk_acc, float* __restrict__ out)
{
  const int bh  = blockIdx.x;          // b*32 + h
  const int b   = bh >> 5, h = bh & 31;
  const int hkv = h >> 4, g = h & 15;
  const int d   = threadIdx.x;

  float m_r[R_], lse_r[R_];
  #pragma unroll
  for (int r = 0; r < R_; ++r) {
    const float* ls = lse_split + ((r*B_ + b)*HKV_ + hkv)*(S_*G_) + g;
    float m = NEGINF;
    #pragma unroll 8
    for (int s2 = 0; s2 < S_; ++s2) m = fmaxf(m, ls[s2*G_]);
    float sum = 0.f;
    #pragma unroll 8
    for (int s2 = 0; s2 < S_; ++s2) sum += __expf(ls[s2*G_] - m);
    m_r[r]   = m;
    lse_r[r] = m + __logf(sum);
  }
  const float M = fmaxf(fmaxf(lse_r[0], lse_r[1]), fmaxf(lse_r[2], lse_r[3]));
  float denom = 0.f, o = 0.f;
  #pragma unroll
  for (int r = 0; r < R_; ++r) {
    const float w = __expf(lse_r[r] - M);
    denom += w;
    const float* cm = chunk_m + (((r*B_ + b)*HKV_ + hkv)*S_)*G_ + g;
    const _Float16* ca = chunk_acc
        + (size_t)(((r*B_ + b)*HKV_ + hkv)*S_)*(G_*D_) + g*D_ + d;
    float a = 0.f;
    #pragma unroll 8
    for (int c = 0; c < S_; ++c)
      a += __expf(cm[c*G_] - m_r[r]) * (float)ca[(size_t)c*(G_*D_)];
    o += w * a;   // faithful: acc_r UNNORMALIZED, weighted by exp(lse_r - M)
  }
  out[(size_t)bh*D_ + d] = o / denom;
}

extern "C" void kernel_launch(void* const* d_in, const int* in_sizes, int n_in,
                              void* d_out, int out_size, void* d_ws, size_t ws_size,
                              hipStream_t stream) {
  const float* q   = (const float*)d_in[0];
  const float* kc  = (const float*)d_in[1];
  const float* vc  = (const float*)d_in[2];
  const int*   bt  = (const int*)d_in[3];
  const int*   len = (const int*)d_in[4];
  float* out = (float*)d_out;
  float* ws  = (float*)d_ws;

  const size_t lse_f = (size_t)R_*B_*HKV_*S_*G_;   // 65536
  float*    lse_split = ws;
  float*    chunk_m   = ws + lse_f;
  _Float16* chunk_acc = (_Float16*)(ws + 2*lse_f);

  fd_stage1<<<dim3(R_*B_*HKV_*S_), dim3(256), 0, stream>>>(
      q, kc, vc, bt, len, lse_split, chunk_m, chunk_acc);
  fd_stage2<<<dim3(B_*HQ_), dim3(128), 0, stream>>>(
      lse_split, chunk_m, chunk_acc, out);
}